// Round 3
// baseline (795.521 us; speedup 1.0000x reference)
//
#include <hip/hip_runtime.h>

#define NN 100000
#define EE 1600000
#define DD 128
#define TD 640
#define EPSV 1e-5f
#define NBLK_SCAN 391   // ceil(NN/256)
#define SB 1024         // stats partial blocks

typedef __attribute__((ext_vector_type(8))) short bf16x8;
typedef __attribute__((ext_vector_type(4))) float f32x4;

__device__ inline unsigned short f2b(float f) {
  union { float f; unsigned u; } x; x.f = f;
  unsigned r = x.u + 0x7fff + ((x.u >> 16) & 1);
  return (unsigned short)(r >> 16);
}
__device__ inline float b2f(unsigned short u) {
  union { unsigned u; float f; } x; x.u = ((unsigned)u) << 16;
  return x.f;
}

// ---------- BN stats, stage 1: vectorized grid-stride, per-column partials
__global__ __launch_bounds__(256) void k_stats_partial(const float* __restrict__ x,
    float* __restrict__ ps, float* __restrict__ pq) {
  float s0=0.f,s1=0.f,s2=0.f,s3=0.f,q0=0.f,q1=0.f,q2=0.f,q3=0.f;
  const float4* x4 = reinterpret_cast<const float4*>(x);
  const int total = NN * DD / 4;
  for (int i = blockIdx.x * 256 + threadIdx.x; i < total; i += SB * 256) {
    float4 v = x4[i];
    s0 += v.x; s1 += v.y; s2 += v.z; s3 += v.w;
    q0 += v.x*v.x; q1 += v.y*v.y; q2 += v.z*v.z; q3 += v.w*v.w;
  }
  // thread's columns: c4 = (t&31)*4 + j  (stride SB*256 and block offset are %32==0)
  __shared__ float ls[256], lq[256];
  int t = threadIdx.x;
  float sv[4] = {s0,s1,s2,s3}, qv[4] = {q0,q1,q2,q3};
#pragma unroll
  for (int j = 0; j < 4; ++j) {
    ls[t] = sv[j]; lq[t] = qv[j];
    __syncthreads();
    if (t < 32) {
      float a = 0.f, b = 0.f;
#pragma unroll
      for (int k = 0; k < 8; ++k) { a += ls[t + 32*k]; b += lq[t + 32*k]; }
      ps[blockIdx.x * DD + t*4 + j] = a;
      pq[blockIdx.x * DD + t*4 + j] = b;
    }
    __syncthreads();
  }
}

// ---------- BN stats, stage 2: one block, 1024 threads (8 segs x 128 cols)
__global__ __launch_bounds__(1024) void k_stats_final(const float* __restrict__ ps,
    const float* __restrict__ pq, const float* __restrict__ g,
    const float* __restrict__ be, float* __restrict__ ssb) {
  __shared__ float ls[1024], lq[1024];
  int t = threadIdx.x;
  int col = t & 127, seg = t >> 7;
  float s = 0.f, q = 0.f;
  for (int b = seg; b < SB; b += 8) { s += ps[b * DD + col]; q += pq[b * DD + col]; }
  ls[t] = s; lq[t] = q;
  __syncthreads();
  if (t < 128) {
#pragma unroll
    for (int k = 1; k < 8; ++k) { s += ls[t + 128*k]; q += lq[t + 128*k]; }
    float mean = s * (1.0f / NN);
    float var  = q * (1.0f / NN) - mean * mean;
    float sc = g[t] * rsqrtf(var + EPSV);
    ssb[t] = sc;
    ssb[DD + t] = be[t] - mean * sc;
  }
}

// ---------- fused BN+ReLU+bf16 cast
__global__ __launch_bounds__(256) void k_act(const float* __restrict__ x,
    const float* __restrict__ ss, unsigned short* __restrict__ A) {
  int i = blockIdx.x * 256 + threadIdx.x;  // [0, NN*DD/4) exactly
  float4 v = reinterpret_cast<const float4*>(x)[i];
  int c4 = (i & 31) * 4;
  float s0 = ss[c4+0], s1 = ss[c4+1], s2 = ss[c4+2], s3 = ss[c4+3];
  float h0 = ss[DD+c4+0], h1 = ss[DD+c4+1], h2 = ss[DD+c4+2], h3 = ss[DD+c4+3];
  ushort4 o;
  o.x = f2b(fmaxf(0.f, v.x * s0 + h0));
  o.y = f2b(fmaxf(0.f, v.y * s1 + h1));
  o.z = f2b(fmaxf(0.f, v.z * s2 + h2));
  o.w = f2b(fmaxf(0.f, v.w * s3 + h3));
  reinterpret_cast<ushort4*>(A)[i] = o;
}

// ---------- weight fp32 -> bf16
__global__ void k_cvt(const float* __restrict__ w, unsigned short* __restrict__ o) {
  int i = blockIdx.x * 256 + threadIdx.x;  // [0, 640*128/4) exactly
  float4 v = reinterpret_cast<const float4*>(w)[i];
  ushort4 u; u.x = f2b(v.x); u.y = f2b(v.y); u.z = f2b(v.z); u.w = f2b(v.w);
  reinterpret_cast<ushort4*>(o)[i] = u;
}

// ---------- CSR build
__global__ void k_zero(int* p, int n) {
  int i = blockIdx.x * 256 + threadIdx.x;
  if (i < n) p[i] = 0;
}
__global__ void k_hist(const int* __restrict__ dst, int* __restrict__ cnt) {
  int i = blockIdx.x * 256 + threadIdx.x;
  if (i < EE) atomicAdd(&cnt[dst[i]], 1);
}
__global__ __launch_bounds__(256) void k_scan_blk(const int* __restrict__ cnt, int* __restrict__ bsum) {
  __shared__ int sh[256];
  int idx = blockIdx.x * 256 + threadIdx.x;
  sh[threadIdx.x] = (idx < NN) ? cnt[idx] : 0;
  __syncthreads();
  for (int off = 128; off > 0; off >>= 1) {
    if (threadIdx.x < off) sh[threadIdx.x] += sh[threadIdx.x + off];
    __syncthreads();
  }
  if (threadIdx.x == 0) bsum[blockIdx.x] = sh[0];
}
__global__ __launch_bounds__(512) void k_scan_top(int* __restrict__ bsum) {
  __shared__ int sh[512];
  int t = threadIdx.x;
  int v = (t < NBLK_SCAN) ? bsum[t] : 0;
  sh[t] = v;
  __syncthreads();
  for (int off = 1; off < 512; off <<= 1) {
    int add = (t >= off) ? sh[t - off] : 0;
    __syncthreads();
    sh[t] += add;
    __syncthreads();
  }
  if (t < NBLK_SCAN) bsum[t] = sh[t] - v;  // exclusive
}
__global__ __launch_bounds__(256) void k_scan_fin(const int* __restrict__ cnt,
    const int* __restrict__ bsum, int* __restrict__ row_ptr, int* __restrict__ cursor) {
  __shared__ int sh[256];
  int idx = blockIdx.x * 256 + threadIdx.x;
  int v = (idx < NN) ? cnt[idx] : 0;
  sh[threadIdx.x] = v;
  __syncthreads();
  for (int off = 1; off < 256; off <<= 1) {
    int add = (threadIdx.x >= off) ? sh[threadIdx.x - off] : 0;
    __syncthreads();
    sh[threadIdx.x] += add;
    __syncthreads();
  }
  int excl = bsum[blockIdx.x] + sh[threadIdx.x] - v;
  if (idx < NN) { row_ptr[idx] = excl; cursor[idx] = excl; }
  if (idx == NN - 1) row_ptr[NN] = excl + v;
}
__global__ void k_scatter(const int* __restrict__ src, const int* __restrict__ dst,
    const int* __restrict__ et, int* __restrict__ cursor, int* __restrict__ payload) {
  int i = blockIdx.x * 256 + threadIdx.x;
  if (i < EE) {
    int pos = atomicAdd(&cursor[dst[i]], 1);
    __builtin_nontemporal_store((src[i] << 3) | et[i], &payload[pos]);
  }
}

// ---------- bf16 MFMA GEMM: H[N,640] = A[N,128] * W^T + bias, stored bf16
// Swapped MFMA operands: lane owns one node row x 4 consecutive cols -> 8B stores.
__global__ __launch_bounds__(256) void k_gemm(const unsigned short* __restrict__ A,
    const unsigned short* __restrict__ W, const float* __restrict__ bias,
    unsigned short* __restrict__ H) {
  const int l = threadIdx.x & 63;
  const int w = threadIdx.x >> 6;
  const int C = blockIdx.y * 64;
  const int lm = l & 15;
  const int hi = l >> 4;
  const int lk = hi * 8;

  bf16x8 bfr[4][4];
#pragma unroll
  for (int kk = 0; kk < 4; ++kk)
#pragma unroll
    for (int f = 0; f < 4; ++f)
      bfr[kk][f] = *reinterpret_cast<const bf16x8*>(W + (C + f * 16 + lm) * DD + kk * 32 + lk);

  float4 bv[4];
#pragma unroll
  for (int f = 0; f < 4; ++f)
    bv[f] = *reinterpret_cast<const float4*>(bias + C + f * 16 + hi * 4);

  const int R = blockIdx.x * 64 + w * 16;
  int arow = R + lm; if (arow >= NN) arow = NN - 1;
  const unsigned short* aptr = A + arow * DD + lk;
  f32x4 acc[4] = {};
#pragma unroll
  for (int kk = 0; kk < 4; ++kk) {
    bf16x8 af = *reinterpret_cast<const bf16x8*>(aptr + kk * 32);
#pragma unroll
    for (int f = 0; f < 4; ++f)
      acc[f] = __builtin_amdgcn_mfma_f32_16x16x32_bf16(bfr[kk][f], af, acc[f], 0, 0, 0);
  }
  // lane holds node n = R+lm, cols C + f*16 + hi*4 + r
  const int n = R + lm;
  if (n < NN) {
    unsigned short* hp = H + n * TD + C + hi * 4;
#pragma unroll
    for (int f = 0; f < 4; ++f) {
      ushort4 o;
      o.x = f2b(acc[f][0] + bv[f].x);
      o.y = f2b(acc[f][1] + bv[f].y);
      o.z = f2b(acc[f][2] + bv[f].z);
      o.w = f2b(acc[f][3] + bv[f].w);
      *reinterpret_cast<ushort4*>(hp + f * 16) = o;
    }
  }
}

// ---------- per-dst segment sum, 1 wave per node, ushort2 per lane
__global__ __launch_bounds__(64) void k_gather(const unsigned short* __restrict__ H,
    const int* __restrict__ rp, const int* __restrict__ pl,
    const float* __restrict__ base, float* __restrict__ y) {
  int m = blockIdx.x;
  int l = threadIdx.x;  // 0..63
  int s = rp[m], e = rp[m + 1];
  float a0 = 0.f, a1 = 0.f;
  if (base) {
    float2 b = reinterpret_cast<const float2*>(base)[m * 64 + l];
    a0 = b.x; a1 = b.y;
  }
  int j = s;
  for (; j + 1 < e; j += 2) {
    int p0 = pl[j], p1 = pl[j + 1];
    ushort2 u0 = reinterpret_cast<const ushort2*>(H + (p0 >> 3) * TD + (p0 & 7) * DD)[l];
    ushort2 u1 = reinterpret_cast<const ushort2*>(H + (p1 >> 3) * TD + (p1 & 7) * DD)[l];
    a0 += b2f(u0.x) + b2f(u1.x);
    a1 += b2f(u0.y) + b2f(u1.y);
  }
  if (j < e) {
    int p0 = pl[j];
    ushort2 u0 = reinterpret_cast<const ushort2*>(H + (p0 >> 3) * TD + (p0 & 7) * DD)[l];
    a0 += b2f(u0.x);
    a1 += b2f(u0.y);
  }
  float2 o; o.x = a0; o.y = a1;
  reinterpret_cast<float2*>(y)[m * 64 + l] = o;
}

extern "C" void kernel_launch(void* const* d_in, const int* in_sizes, int n_in,
                              void* d_out, int out_size, void* d_ws, size_t ws_size,
                              hipStream_t stream) {
  const float* features = (const float*)d_in[0];
  const int*   src   = (const int*)d_in[1];
  const int*   dst   = (const int*)d_in[2];
  const int*   etype = (const int*)d_in[3];
  const float* w1  = (const float*)d_in[4];
  const float* b1  = (const float*)d_in[5];
  const float* g1  = (const float*)d_in[6];
  const float* be1 = (const float*)d_in[7];
  const float* w2  = (const float*)d_in[8];
  const float* b2  = (const float*)d_in[9];
  const float* g2  = (const float*)d_in[10];
  const float* be2 = (const float*)d_in[11];

  char* ws = (char*)d_ws;
  unsigned short* Ab   = (unsigned short*)(ws + 0);            // 25,600,000 B
  // ps/pq alias the Ab region: stats for round k complete before k_act
  // overwrites Ab, and ssb (their only consumer's output) lives elsewhere.
  float*          ps   = (float*)(ws + 0);                     // 524,288 B
  float*          pq   = (float*)(ws + 524288);                // 524,288 B
  unsigned short* Hb   = (unsigned short*)(ws + 25600000);     // 128,000,000 B
  float*          y1   = (float*)(ws + 153600000);             // 51,200,000 B
  unsigned short* w1b  = (unsigned short*)(ws + 204800000);    // 163,840 B
  unsigned short* w2b  = (unsigned short*)(ws + 204963840);    // 163,840 B
  float*          ssb  = (float*)(ws + 205127680);             // 1,024 B
  int*            rowp = (int*)(ws + 205390848);               // 400,016 B
  int*            curs = (int*)(ws + 205790864);               // 400,000 B
  int*            payl = (int*)(ws + 206190864);               // 6,400,000 B
  int*            bsum = (int*)(ws + 212590864);               // 2,048 B
  // total: 212,592,912 B (same footprint as the passing R2 layout)

  // CSR build (shared by both rounds)
  k_zero<<<(NN + 255) / 256, 256, 0, stream>>>(curs, NN);
  k_hist<<<(EE + 255) / 256, 256, 0, stream>>>(dst, curs);
  k_scan_blk<<<NBLK_SCAN, 256, 0, stream>>>(curs, bsum);
  k_scan_top<<<1, 512, 0, stream>>>(bsum);
  k_scan_fin<<<NBLK_SCAN, 256, 0, stream>>>(curs, bsum, rowp, curs);
  k_scatter<<<(EE + 255) / 256, 256, 0, stream>>>(src, dst, etype, curs, payl);

  // weights -> bf16
  k_cvt<<<80, 256, 0, stream>>>(w1, w1b);
  k_cvt<<<80, 256, 0, stream>>>(w2, w2b);

  dim3 gemm_grid(1563, 10);

  // ---- round 1
  k_stats_partial<<<SB, 256, 0, stream>>>(features, ps, pq);
  k_stats_final<<<1, 1024, 0, stream>>>(ps, pq, g1, be1, ssb);
  k_act<<<12500, 256, 0, stream>>>(features, ssb, Ab);
  k_gemm<<<gemm_grid, 256, 0, stream>>>(Ab, w1b, b1, Hb);
  k_gather<<<NN, 64, 0, stream>>>(Hb, rowp, payl, nullptr, y1);

  // ---- round 2
  k_stats_partial<<<SB, 256, 0, stream>>>(y1, ps, pq);
  k_stats_final<<<1, 1024, 0, stream>>>(ps, pq, g2, be2, ssb);
  k_act<<<12500, 256, 0, stream>>>(y1, ssb, Ab);
  k_gemm<<<gemm_grid, 256, 0, stream>>>(Ab, w2b, b2, Hb);
  k_gather<<<NN, 64, 0, stream>>>(Hb, rowp, payl, features, (float*)d_out);
}

// Round 4
// 690.428 us; speedup vs baseline: 1.1522x; 1.1522x over previous
//
#include <hip/hip_runtime.h>

#define NN 100000
#define EE 1600000
#define DD 128
#define TD 640
#define EPSV 1e-5f
#define NBLK_SCAN 391   // ceil(NN/256)
#define SB 1024         // stats partial blocks

typedef __attribute__((ext_vector_type(8))) short bf16x8;
typedef __attribute__((ext_vector_type(4))) float f32x4;

__device__ inline unsigned short f2b(float f) {
  union { float f; unsigned u; } x; x.f = f;
  unsigned r = x.u + 0x7fff + ((x.u >> 16) & 1);
  return (unsigned short)(r >> 16);
}
__device__ inline float b2f(unsigned short u) {
  union { unsigned u; float f; } x; x.u = ((unsigned)u) << 16;
  return x.f;
}

// ---------- BN stats, stage 1: vectorized grid-stride, per-column partials
__global__ __launch_bounds__(256) void k_stats_partial(const float* __restrict__ x,
    float* __restrict__ ps, float* __restrict__ pq) {
  float s0=0.f,s1=0.f,s2=0.f,s3=0.f,q0=0.f,q1=0.f,q2=0.f,q3=0.f;
  const float4* x4 = reinterpret_cast<const float4*>(x);
  const int total = NN * DD / 4;
  for (int i = blockIdx.x * 256 + threadIdx.x; i < total; i += SB * 256) {
    float4 v = x4[i];
    s0 += v.x; s1 += v.y; s2 += v.z; s3 += v.w;
    q0 += v.x*v.x; q1 += v.y*v.y; q2 += v.z*v.z; q3 += v.w*v.w;
  }
  __shared__ float ls[256], lq[256];
  int t = threadIdx.x;
  float sv[4] = {s0,s1,s2,s3}, qv[4] = {q0,q1,q2,q3};
#pragma unroll
  for (int j = 0; j < 4; ++j) {
    ls[t] = sv[j]; lq[t] = qv[j];
    __syncthreads();
    if (t < 32) {
      float a = 0.f, b = 0.f;
#pragma unroll
      for (int k = 0; k < 8; ++k) { a += ls[t + 32*k]; b += lq[t + 32*k]; }
      ps[blockIdx.x * DD + t*4 + j] = a;
      pq[blockIdx.x * DD + t*4 + j] = b;
    }
    __syncthreads();
  }
}

// ---------- BN stats, stage 2
__global__ __launch_bounds__(1024) void k_stats_final(const float* __restrict__ ps,
    const float* __restrict__ pq, const float* __restrict__ g,
    const float* __restrict__ be, float* __restrict__ ssb) {
  __shared__ float ls[1024], lq[1024];
  int t = threadIdx.x;
  int col = t & 127, seg = t >> 7;
  float s = 0.f, q = 0.f;
  for (int b = seg; b < SB; b += 8) { s += ps[b * DD + col]; q += pq[b * DD + col]; }
  ls[t] = s; lq[t] = q;
  __syncthreads();
  if (t < 128) {
#pragma unroll
    for (int k = 1; k < 8; ++k) { s += ls[t + 128*k]; q += lq[t + 128*k]; }
    float mean = s * (1.0f / NN);
    float var  = q * (1.0f / NN) - mean * mean;
    float sc = g[t] * rsqrtf(var + EPSV);
    ssb[t] = sc;
    ssb[DD + t] = be[t] - mean * sc;
  }
}

// ---------- fused BN+ReLU+bf16 cast
__global__ __launch_bounds__(256) void k_act(const float* __restrict__ x,
    const float* __restrict__ ss, unsigned short* __restrict__ A) {
  int i = blockIdx.x * 256 + threadIdx.x;  // [0, NN*DD/4) exactly
  float4 v = reinterpret_cast<const float4*>(x)[i];
  int c4 = (i & 31) * 4;
  float s0 = ss[c4+0], s1 = ss[c4+1], s2 = ss[c4+2], s3 = ss[c4+3];
  float h0 = ss[DD+c4+0], h1 = ss[DD+c4+1], h2 = ss[DD+c4+2], h3 = ss[DD+c4+3];
  ushort4 o;
  o.x = f2b(fmaxf(0.f, v.x * s0 + h0));
  o.y = f2b(fmaxf(0.f, v.y * s1 + h1));
  o.z = f2b(fmaxf(0.f, v.z * s2 + h2));
  o.w = f2b(fmaxf(0.f, v.w * s3 + h3));
  reinterpret_cast<ushort4*>(A)[i] = o;
}

// ---------- weight fp32 -> bf16
__global__ void k_cvt(const float* __restrict__ w, unsigned short* __restrict__ o) {
  int i = blockIdx.x * 256 + threadIdx.x;
  float4 v = reinterpret_cast<const float4*>(w)[i];
  ushort4 u; u.x = f2b(v.x); u.y = f2b(v.y); u.z = f2b(v.z); u.w = f2b(v.w);
  reinterpret_cast<ushort4*>(o)[i] = u;
}

// ---------- CSR build
__global__ void k_zero(int* p, int n) {
  int i = blockIdx.x * 256 + threadIdx.x;
  if (i < n) p[i] = 0;
}
__global__ void k_hist(const int* __restrict__ dst, int* __restrict__ cnt) {
  int i = blockIdx.x * 256 + threadIdx.x;
  if (i < EE) atomicAdd(&cnt[dst[i]], 1);
}
__global__ __launch_bounds__(256) void k_scan_blk(const int* __restrict__ cnt, int* __restrict__ bsum) {
  __shared__ int sh[256];
  int idx = blockIdx.x * 256 + threadIdx.x;
  sh[threadIdx.x] = (idx < NN) ? cnt[idx] : 0;
  __syncthreads();
  for (int off = 128; off > 0; off >>= 1) {
    if (threadIdx.x < off) sh[threadIdx.x] += sh[threadIdx.x + off];
    __syncthreads();
  }
  if (threadIdx.x == 0) bsum[blockIdx.x] = sh[0];
}
__global__ __launch_bounds__(512) void k_scan_top(int* __restrict__ bsum) {
  __shared__ int sh[512];
  int t = threadIdx.x;
  int v = (t < NBLK_SCAN) ? bsum[t] : 0;
  sh[t] = v;
  __syncthreads();
  for (int off = 1; off < 512; off <<= 1) {
    int add = (t >= off) ? sh[t - off] : 0;
    __syncthreads();
    sh[t] += add;
    __syncthreads();
  }
  if (t < NBLK_SCAN) bsum[t] = sh[t] - v;  // exclusive
}
__global__ __launch_bounds__(256) void k_scan_fin(const int* __restrict__ cnt,
    const int* __restrict__ bsum, int* __restrict__ row_ptr, int* __restrict__ cursor) {
  __shared__ int sh[256];
  int idx = blockIdx.x * 256 + threadIdx.x;
  int v = (idx < NN) ? cnt[idx] : 0;
  sh[threadIdx.x] = v;
  __syncthreads();
  for (int off = 1; off < 256; off <<= 1) {
    int add = (threadIdx.x >= off) ? sh[threadIdx.x - off] : 0;
    __syncthreads();
    sh[threadIdx.x] += add;
    __syncthreads();
  }
  int excl = bsum[blockIdx.x] + sh[threadIdx.x] - v;
  if (idx < NN) { row_ptr[idx] = excl; cursor[idx] = excl; }
  if (idx == NN - 1) row_ptr[NN] = excl + v;
}
__global__ void k_scatter(const int* __restrict__ src, const int* __restrict__ dst,
    const int* __restrict__ et, int* __restrict__ cursor, int* __restrict__ payload) {
  int i = blockIdx.x * 256 + threadIdx.x;
  if (i < EE) {
    int pos = atomicAdd(&cursor[dst[i]], 1);
    __builtin_nontemporal_store((src[i] << 3) | et[i], &payload[pos]);
  }
}

// ---------- bf16 MFMA GEMM: H[N,640] = A[N,128] * W^T + bias, stored bf16
// One block = 64 rows x ALL 640 cols. A frags in regs (loaded once); W strips
// (64 cols x 128 K = 16 KB) double-buffered in LDS with XOR bank swizzle.
// Full H rows written by one block -> complete cache lines, no RMW fetch.
__global__ __launch_bounds__(256) void k_gemm(const unsigned short* __restrict__ A,
    const unsigned short* __restrict__ W, const float* __restrict__ bias,
    unsigned short* __restrict__ H) {
  __shared__ unsigned short wlds[2][8192];  // 2 x 16 KB
  const int t = threadIdx.x;
  const int l = t & 63;
  const int w = t >> 6;
  const int lm = l & 15;
  const int hi = l >> 4;
  const int R = blockIdx.x * 64 + w * 16;

  // A fragments: wave's 16 rows, K=128 in 4 chunks
  int arow = R + lm; if (arow >= NN) arow = NN - 1;
  const unsigned short* aptr = A + arow * DD + hi * 8;
  bf16x8 af[4];
#pragma unroll
  for (int kk = 0; kk < 4; ++kk)
    af[kk] = *reinterpret_cast<const bf16x8*>(aptr + kk * 32);

  // stage strip 0
#pragma unroll
  for (int k = 0; k < 4; ++k) {
    int i = k * 256 + t;
    int r = i >> 4, b = (i & 15) * 16;
    float4 v = *reinterpret_cast<const float4*>(
        reinterpret_cast<const char*>(W) + r * 256 + b);
    *reinterpret_cast<float4*>(
        reinterpret_cast<char*>(wlds[0]) + r * 256 + (b ^ ((r & 7) << 4))) = v;
  }
  __syncthreads();

  const int r0 = R + hi * 4;
#pragma unroll 1
  for (int cb = 0; cb < 10; ++cb) {
    const int buf = cb & 1;
    if (cb < 9) {  // prefetch next strip into other buffer
#pragma unroll
      for (int k = 0; k < 4; ++k) {
        int i = k * 256 + t;
        int r = i >> 4, b = (i & 15) * 16;
        float4 v = *reinterpret_cast<const float4*>(
            reinterpret_cast<const char*>(W) + ((cb + 1) * 64 + r) * 256 + b);
        *reinterpret_cast<float4*>(
            reinterpret_cast<char*>(wlds[buf ^ 1]) + r * 256 + (b ^ ((r & 7) << 4))) = v;
      }
    }
    f32x4 acc[4] = {};
#pragma unroll
    for (int kk = 0; kk < 4; ++kk) {
#pragma unroll
      for (int f = 0; f < 4; ++f) {
        int rr = f * 16 + lm;
        bf16x8 bfr = *reinterpret_cast<const bf16x8*>(
            reinterpret_cast<char*>(wlds[buf]) + rr * 256 +
            ((kk * 64 + hi * 16) ^ ((rr & 7) << 4)));
        acc[f] = __builtin_amdgcn_mfma_f32_16x16x32_bf16(af[kk], bfr, acc[f], 0, 0, 0);
      }
    }
    // epilogue: sector-aligned 2B stores (16 lanes x 2B = 32B contiguous)
#pragma unroll
    for (int f = 0; f < 4; ++f) {
      int col = cb * 64 + f * 16 + lm;
      float bv = bias[col];
#pragma unroll
      for (int r = 0; r < 4; ++r) {
        int row = r0 + r;
        if (row < NN) H[row * TD + col] = f2b(acc[f][r] + bv);
      }
    }
    __syncthreads();
  }
}

// ---------- per-dst segment sum, 4 nodes per block (1 wave each)
__global__ __launch_bounds__(256) void k_gather(const unsigned short* __restrict__ H,
    const int* __restrict__ rp, const int* __restrict__ pl,
    const float* __restrict__ base, float* __restrict__ y) {
  int m = blockIdx.x * 4 + (threadIdx.x >> 6);
  int l = threadIdx.x & 63;
  int s = rp[m], e = rp[m + 1];
  float a0 = 0.f, a1 = 0.f;
  if (base) {
    float2 b = reinterpret_cast<const float2*>(base)[m * 64 + l];
    a0 = b.x; a1 = b.y;
  }
  int j = s;
  for (; j + 1 < e; j += 2) {
    int p0 = pl[j], p1 = pl[j + 1];
    ushort2 u0 = reinterpret_cast<const ushort2*>(H + (p0 >> 3) * TD + (p0 & 7) * DD)[l];
    ushort2 u1 = reinterpret_cast<const ushort2*>(H + (p1 >> 3) * TD + (p1 & 7) * DD)[l];
    a0 += b2f(u0.x) + b2f(u1.x);
    a1 += b2f(u0.y) + b2f(u1.y);
  }
  if (j < e) {
    int p0 = pl[j];
    ushort2 u0 = reinterpret_cast<const ushort2*>(H + (p0 >> 3) * TD + (p0 & 7) * DD)[l];
    a0 += b2f(u0.x);
    a1 += b2f(u0.y);
  }
  float2 o; o.x = a0; o.y = a1;
  reinterpret_cast<float2*>(y)[m * 64 + l] = o;
}

extern "C" void kernel_launch(void* const* d_in, const int* in_sizes, int n_in,
                              void* d_out, int out_size, void* d_ws, size_t ws_size,
                              hipStream_t stream) {
  const float* features = (const float*)d_in[0];
  const int*   src   = (const int*)d_in[1];
  const int*   dst   = (const int*)d_in[2];
  const int*   etype = (const int*)d_in[3];
  const float* w1  = (const float*)d_in[4];
  const float* b1  = (const float*)d_in[5];
  const float* g1  = (const float*)d_in[6];
  const float* be1 = (const float*)d_in[7];
  const float* w2  = (const float*)d_in[8];
  const float* b2  = (const float*)d_in[9];
  const float* g2  = (const float*)d_in[10];
  const float* be2 = (const float*)d_in[11];

  char* ws = (char*)d_ws;
  unsigned short* Ab   = (unsigned short*)(ws + 0);            // 25,600,000 B
  float*          ps   = (float*)(ws + 0);                     // aliases Ab (dead before k_act)
  float*          pq   = (float*)(ws + 524288);
  unsigned short* Hb   = (unsigned short*)(ws + 25600000);     // 128,000,000 B
  float*          y1   = (float*)(ws + 153600000);             // 51,200,000 B
  unsigned short* w1b  = (unsigned short*)(ws + 204800000);    // 163,840 B
  unsigned short* w2b  = (unsigned short*)(ws + 204963840);    // 163,840 B
  float*          ssb  = (float*)(ws + 205127680);             // 1,024 B
  int*            rowp = (int*)(ws + 205390848);               // 400,016 B
  int*            curs = (int*)(ws + 205790864);               // 400,000 B
  int*            payl = (int*)(ws + 206190864);               // 6,400,000 B
  int*            bsum = (int*)(ws + 212590864);               // 2,048 B

  // CSR build (shared by both rounds)
  k_zero<<<(NN + 255) / 256, 256, 0, stream>>>(curs, NN);
  k_hist<<<(EE + 255) / 256, 256, 0, stream>>>(dst, curs);
  k_scan_blk<<<NBLK_SCAN, 256, 0, stream>>>(curs, bsum);
  k_scan_top<<<1, 512, 0, stream>>>(bsum);
  k_scan_fin<<<NBLK_SCAN, 256, 0, stream>>>(curs, bsum, rowp, curs);
  k_scatter<<<(EE + 255) / 256, 256, 0, stream>>>(src, dst, etype, curs, payl);

  // weights -> bf16
  k_cvt<<<80, 256, 0, stream>>>(w1, w1b);
  k_cvt<<<80, 256, 0, stream>>>(w2, w2b);

  // ---- round 1
  k_stats_partial<<<SB, 256, 0, stream>>>(features, ps, pq);
  k_stats_final<<<1, 1024, 0, stream>>>(ps, pq, g1, be1, ssb);
  k_act<<<12500, 256, 0, stream>>>(features, ssb, Ab);
  k_gemm<<<1563, 256, 0, stream>>>(Ab, w1b, b1, Hb);
  k_gather<<<NN / 4, 256, 0, stream>>>(Hb, rowp, payl, nullptr, y1);

  // ---- round 2
  k_stats_partial<<<SB, 256, 0, stream>>>(y1, ps, pq);
  k_stats_final<<<1, 1024, 0, stream>>>(ps, pq, g2, be2, ssb);
  k_act<<<12500, 256, 0, stream>>>(y1, ssb, Ab);
  k_gemm<<<1563, 256, 0, stream>>>(Ab, w2b, b2, Hb);
  k_gather<<<NN / 4, 256, 0, stream>>>(Hb, rowp, payl, features, (float*)d_out);
}

// Round 5
// 629.028 us; speedup vs baseline: 1.2647x; 1.0976x over previous
//
#include <hip/hip_runtime.h>

#define NN 100000
#define EE 1600000
#define DD 128
#define TD 640
#define EPSV 1e-5f
#define NBLK_SCAN 391   // ceil(NN/256)
#define SB 1024         // stats partial blocks
#define NRANGE 8        // XCD count; node range slice = NN/8
#define RSZ 12500       // NN / NRANGE
#define NCHUNK 256      // edge chunks
#define CSZ 6250        // EE / NCHUNK

typedef __attribute__((ext_vector_type(8))) short bf16x8;
typedef __attribute__((ext_vector_type(4))) float f32x4;

__device__ inline unsigned short f2b(float f) {
  union { float f; unsigned u; } x; x.f = f;
  unsigned r = x.u + 0x7fff + ((x.u >> 16) & 1);
  return (unsigned short)(r >> 16);
}
__device__ inline float b2f(unsigned short u) {
  union { unsigned u; float f; } x; x.u = ((unsigned)u) << 16;
  return x.f;
}

// ---------- BN stats, stage 1: vectorized grid-stride, per-column partials
__global__ __launch_bounds__(256) void k_stats_partial(const float* __restrict__ x,
    float* __restrict__ ps, float* __restrict__ pq) {
  float s0=0.f,s1=0.f,s2=0.f,s3=0.f,q0=0.f,q1=0.f,q2=0.f,q3=0.f;
  const float4* x4 = reinterpret_cast<const float4*>(x);
  const int total = NN * DD / 4;
  for (int i = blockIdx.x * 256 + threadIdx.x; i < total; i += SB * 256) {
    float4 v = x4[i];
    s0 += v.x; s1 += v.y; s2 += v.z; s3 += v.w;
    q0 += v.x*v.x; q1 += v.y*v.y; q2 += v.z*v.z; q3 += v.w*v.w;
  }
  __shared__ float ls[256], lq[256];
  int t = threadIdx.x;
  float sv[4] = {s0,s1,s2,s3}, qv[4] = {q0,q1,q2,q3};
#pragma unroll
  for (int j = 0; j < 4; ++j) {
    ls[t] = sv[j]; lq[t] = qv[j];
    __syncthreads();
    if (t < 32) {
      float a = 0.f, b = 0.f;
#pragma unroll
      for (int k = 0; k < 8; ++k) { a += ls[t + 32*k]; b += lq[t + 32*k]; }
      ps[blockIdx.x * DD + t*4 + j] = a;
      pq[blockIdx.x * DD + t*4 + j] = b;
    }
    __syncthreads();
  }
}

// ---------- BN stats, stage 2
__global__ __launch_bounds__(1024) void k_stats_final(const float* __restrict__ ps,
    const float* __restrict__ pq, const float* __restrict__ g,
    const float* __restrict__ be, float* __restrict__ ssb) {
  __shared__ float ls[1024], lq[1024];
  int t = threadIdx.x;
  int col = t & 127, seg = t >> 7;
  float s = 0.f, q = 0.f;
  for (int b = seg; b < SB; b += 8) { s += ps[b * DD + col]; q += pq[b * DD + col]; }
  ls[t] = s; lq[t] = q;
  __syncthreads();
  if (t < 128) {
#pragma unroll
    for (int k = 1; k < 8; ++k) { s += ls[t + 128*k]; q += lq[t + 128*k]; }
    float mean = s * (1.0f / NN);
    float var  = q * (1.0f / NN) - mean * mean;
    float sc = g[t] * rsqrtf(var + EPSV);
    ssb[t] = sc;
    ssb[DD + t] = be[t] - mean * sc;
  }
}

// ---------- fused BN+ReLU+bf16 cast
__global__ __launch_bounds__(256) void k_act(const float* __restrict__ x,
    const float* __restrict__ ss, unsigned short* __restrict__ A) {
  int i = blockIdx.x * 256 + threadIdx.x;  // [0, NN*DD/4) exactly
  float4 v = reinterpret_cast<const float4*>(x)[i];
  int c4 = (i & 31) * 4;
  float s0 = ss[c4+0], s1 = ss[c4+1], s2 = ss[c4+2], s3 = ss[c4+3];
  float h0 = ss[DD+c4+0], h1 = ss[DD+c4+1], h2 = ss[DD+c4+2], h3 = ss[DD+c4+3];
  ushort4 o;
  o.x = f2b(fmaxf(0.f, v.x * s0 + h0));
  o.y = f2b(fmaxf(0.f, v.y * s1 + h1));
  o.z = f2b(fmaxf(0.f, v.z * s2 + h2));
  o.w = f2b(fmaxf(0.f, v.w * s3 + h3));
  reinterpret_cast<ushort4*>(A)[i] = o;
}

// ---------- weight fp32 -> bf16
__global__ void k_cvt(const float* __restrict__ w, unsigned short* __restrict__ o) {
  int i = blockIdx.x * 256 + threadIdx.x;
  float4 v = reinterpret_cast<const float4*>(w)[i];
  ushort4 u; u.x = f2b(v.x); u.y = f2b(v.y); u.z = f2b(v.z); u.w = f2b(v.w);
  reinterpret_cast<ushort4*>(o)[i] = u;
}

// ---------- CSR build
__global__ void k_zero(int* p, int n) {
  int i = blockIdx.x * 256 + threadIdx.x;
  if (i < n) p[i] = 0;
}
// XCD-sliced histogram: block handles chunk (blockIdx>>3), node range (blockIdx&7).
// Atomics for a node range come only from blocks with the same blockIdx&7
// (round-robin -> same XCD), keeping the cnt slice hot in one L2.
__global__ __launch_bounds__(256) void k_hist(const int* __restrict__ dst,
    int* __restrict__ cnt) {
  const int range = blockIdx.x & (NRANGE - 1);
  const int chunk = blockIdx.x >> 3;
  const int lo = range * RSZ;
  const int base = chunk * CSZ;
  for (int i = base + threadIdx.x; i < base + CSZ; i += 256) {
    int d = dst[i];
    if ((unsigned)(d - lo) < RSZ) atomicAdd(&cnt[d], 1);
  }
}
__global__ __launch_bounds__(256) void k_scan_blk(const int* __restrict__ cnt, int* __restrict__ bsum) {
  __shared__ int sh[256];
  int idx = blockIdx.x * 256 + threadIdx.x;
  sh[threadIdx.x] = (idx < NN) ? cnt[idx] : 0;
  __syncthreads();
  for (int off = 128; off > 0; off >>= 1) {
    if (threadIdx.x < off) sh[threadIdx.x] += sh[threadIdx.x + off];
    __syncthreads();
  }
  if (threadIdx.x == 0) bsum[blockIdx.x] = sh[0];
}
__global__ __launch_bounds__(512) void k_scan_top(int* __restrict__ bsum) {
  __shared__ int sh[512];
  int t = threadIdx.x;
  int v = (t < NBLK_SCAN) ? bsum[t] : 0;
  sh[t] = v;
  __syncthreads();
  for (int off = 1; off < 512; off <<= 1) {
    int add = (t >= off) ? sh[t - off] : 0;
    __syncthreads();
    sh[t] += add;
    __syncthreads();
  }
  if (t < NBLK_SCAN) bsum[t] = sh[t] - v;  // exclusive
}
__global__ __launch_bounds__(256) void k_scan_fin(const int* __restrict__ cnt,
    const int* __restrict__ bsum, int* __restrict__ row_ptr, int* __restrict__ cursor) {
  __shared__ int sh[256];
  int idx = blockIdx.x * 256 + threadIdx.x;
  int v = (idx < NN) ? cnt[idx] : 0;
  sh[threadIdx.x] = v;
  __syncthreads();
  for (int off = 1; off < 256; off <<= 1) {
    int add = (threadIdx.x >= off) ? sh[threadIdx.x - off] : 0;
    __syncthreads();
    sh[threadIdx.x] += add;
    __syncthreads();
  }
  int excl = bsum[blockIdx.x] + sh[threadIdx.x] - v;
  if (idx < NN) { row_ptr[idx] = excl; cursor[idx] = excl; }
  if (idx == NN - 1) row_ptr[NN] = excl + v;
}
// XCD-sliced scatter: payload positions for one node range form a contiguous
// slice; with blockIdx&7 -> XCD round-robin, all writes to that slice come
// from one XCD -> full 64B lines assemble in its L2 before eviction.
__global__ __launch_bounds__(256) void k_scatter(const int* __restrict__ src,
    const int* __restrict__ dst, const int* __restrict__ et,
    int* __restrict__ cursor, int* __restrict__ payload) {
  const int range = blockIdx.x & (NRANGE - 1);
  const int chunk = blockIdx.x >> 3;
  const int lo = range * RSZ;
  const int base = chunk * CSZ;
  for (int i = base + threadIdx.x; i < base + CSZ; i += 256) {
    int d = dst[i];
    if ((unsigned)(d - lo) < RSZ) {
      int pos = atomicAdd(&cursor[d], 1);
      payload[pos] = (src[i] << 3) | et[i];
    }
  }
}

// ---------- bf16 MFMA GEMM: H[N,640] = A[N,128] * W^T + bias, stored bf16
__global__ __launch_bounds__(256) void k_gemm(const unsigned short* __restrict__ A,
    const unsigned short* __restrict__ W, const float* __restrict__ bias,
    unsigned short* __restrict__ H) {
  __shared__ unsigned short wlds[2][8192];  // 2 x 16 KB
  const int t = threadIdx.x;
  const int l = t & 63;
  const int w = t >> 6;
  const int lm = l & 15;
  const int hi = l >> 4;
  const int R = blockIdx.x * 64 + w * 16;

  int arow = R + lm; if (arow >= NN) arow = NN - 1;
  const unsigned short* aptr = A + arow * DD + hi * 8;
  bf16x8 af[4];
#pragma unroll
  for (int kk = 0; kk < 4; ++kk)
    af[kk] = *reinterpret_cast<const bf16x8*>(aptr + kk * 32);

#pragma unroll
  for (int k = 0; k < 4; ++k) {
    int i = k * 256 + t;
    int r = i >> 4, b = (i & 15) * 16;
    float4 v = *reinterpret_cast<const float4*>(
        reinterpret_cast<const char*>(W) + r * 256 + b);
    *reinterpret_cast<float4*>(
        reinterpret_cast<char*>(wlds[0]) + r * 256 + (b ^ ((r & 7) << 4))) = v;
  }
  __syncthreads();

  const int r0 = R + hi * 4;
#pragma unroll 1
  for (int cb = 0; cb < 10; ++cb) {
    const int buf = cb & 1;
    if (cb < 9) {
#pragma unroll
      for (int k = 0; k < 4; ++k) {
        int i = k * 256 + t;
        int r = i >> 4, b = (i & 15) * 16;
        float4 v = *reinterpret_cast<const float4*>(
            reinterpret_cast<const char*>(W) + ((cb + 1) * 64 + r) * 256 + b);
        *reinterpret_cast<float4*>(
            reinterpret_cast<char*>(wlds[buf ^ 1]) + r * 256 + (b ^ ((r & 7) << 4))) = v;
      }
    }
    f32x4 acc[4] = {};
#pragma unroll
    for (int kk = 0; kk < 4; ++kk) {
#pragma unroll
      for (int f = 0; f < 4; ++f) {
        int rr = f * 16 + lm;
        bf16x8 bfr = *reinterpret_cast<const bf16x8*>(
            reinterpret_cast<char*>(wlds[buf]) + rr * 256 +
            ((kk * 64 + hi * 16) ^ ((rr & 7) << 4)));
        acc[f] = __builtin_amdgcn_mfma_f32_16x16x32_bf16(af[kk], bfr, acc[f], 0, 0, 0);
      }
    }
#pragma unroll
    for (int f = 0; f < 4; ++f) {
      int col = cb * 64 + f * 16 + lm;
      float bv = bias[col];
#pragma unroll
      for (int r = 0; r < 4; ++r) {
        int row = r0 + r;
        if (row < NN) H[row * TD + col] = f2b(acc[f][r] + bv);
      }
    }
    __syncthreads();
  }
}

// ---------- per-dst segment sum, 4 nodes per block (1 wave each)
__global__ __launch_bounds__(256) void k_gather(const unsigned short* __restrict__ H,
    const int* __restrict__ rp, const int* __restrict__ pl,
    const float* __restrict__ base, float* __restrict__ y) {
  int m = blockIdx.x * 4 + (threadIdx.x >> 6);
  int l = threadIdx.x & 63;
  int s = rp[m], e = rp[m + 1];
  float a0 = 0.f, a1 = 0.f;
  if (base) {
    float2 b = reinterpret_cast<const float2*>(base)[m * 64 + l];
    a0 = b.x; a1 = b.y;
  }
  int j = s;
  for (; j + 1 < e; j += 2) {
    int p0 = pl[j], p1 = pl[j + 1];
    ushort2 u0 = reinterpret_cast<const ushort2*>(H + (p0 >> 3) * TD + (p0 & 7) * DD)[l];
    ushort2 u1 = reinterpret_cast<const ushort2*>(H + (p1 >> 3) * TD + (p1 & 7) * DD)[l];
    a0 += b2f(u0.x) + b2f(u1.x);
    a1 += b2f(u0.y) + b2f(u1.y);
  }
  if (j < e) {
    int p0 = pl[j];
    ushort2 u0 = reinterpret_cast<const ushort2*>(H + (p0 >> 3) * TD + (p0 & 7) * DD)[l];
    a0 += b2f(u0.x);
    a1 += b2f(u0.y);
  }
  float2 o; o.x = a0; o.y = a1;
  reinterpret_cast<float2*>(y)[m * 64 + l] = o;
}

extern "C" void kernel_launch(void* const* d_in, const int* in_sizes, int n_in,
                              void* d_out, int out_size, void* d_ws, size_t ws_size,
                              hipStream_t stream) {
  const float* features = (const float*)d_in[0];
  const int*   src   = (const int*)d_in[1];
  const int*   dst   = (const int*)d_in[2];
  const int*   etype = (const int*)d_in[3];
  const float* w1  = (const float*)d_in[4];
  const float* b1  = (const float*)d_in[5];
  const float* g1  = (const float*)d_in[6];
  const float* be1 = (const float*)d_in[7];
  const float* w2  = (const float*)d_in[8];
  const float* b2  = (const float*)d_in[9];
  const float* g2  = (const float*)d_in[10];
  const float* be2 = (const float*)d_in[11];

  char* ws = (char*)d_ws;
  unsigned short* Ab   = (unsigned short*)(ws + 0);            // 25,600,000 B
  float*          ps   = (float*)(ws + 0);                     // aliases Ab (dead before k_act)
  float*          pq   = (float*)(ws + 524288);
  unsigned short* Hb   = (unsigned short*)(ws + 25600000);     // 128,000,000 B
  float*          y1   = (float*)(ws + 153600000);             // 51,200,000 B
  unsigned short* w1b  = (unsigned short*)(ws + 204800000);    // 163,840 B
  unsigned short* w2b  = (unsigned short*)(ws + 204963840);    // 163,840 B
  float*          ssb  = (float*)(ws + 205127680);             // 1,024 B
  int*            rowp = (int*)(ws + 205390848);               // 400,016 B
  int*            curs = (int*)(ws + 205790864);               // 400,000 B
  int*            payl = (int*)(ws + 206190864);               // 6,400,000 B
  int*            bsum = (int*)(ws + 212590864);               // 2,048 B

  // CSR build (shared by both rounds)
  k_zero<<<(NN + 255) / 256, 256, 0, stream>>>(curs, NN);
  k_hist<<<NRANGE * NCHUNK, 256, 0, stream>>>(dst, curs);
  k_scan_blk<<<NBLK_SCAN, 256, 0, stream>>>(curs, bsum);
  k_scan_top<<<1, 512, 0, stream>>>(bsum);
  k_scan_fin<<<NBLK_SCAN, 256, 0, stream>>>(curs, bsum, rowp, curs);
  k_scatter<<<NRANGE * NCHUNK, 256, 0, stream>>>(src, dst, etype, curs, payl);

  // weights -> bf16
  k_cvt<<<80, 256, 0, stream>>>(w1, w1b);
  k_cvt<<<80, 256, 0, stream>>>(w2, w2b);

  // ---- round 1
  k_stats_partial<<<SB, 256, 0, stream>>>(features, ps, pq);
  k_stats_final<<<1, 1024, 0, stream>>>(ps, pq, g1, be1, ssb);
  k_act<<<12500, 256, 0, stream>>>(features, ssb, Ab);
  k_gemm<<<1563, 256, 0, stream>>>(Ab, w1b, b1, Hb);
  k_gather<<<NN / 4, 256, 0, stream>>>(Hb, rowp, payl, nullptr, y1);

  // ---- round 2
  k_stats_partial<<<SB, 256, 0, stream>>>(y1, ps, pq);
  k_stats_final<<<1, 1024, 0, stream>>>(ps, pq, g2, be2, ssb);
  k_act<<<12500, 256, 0, stream>>>(y1, ssb, Ab);
  k_gemm<<<1563, 256, 0, stream>>>(Ab, w2b, b2, Hb);
  k_gather<<<NN / 4, 256, 0, stream>>>(Hb, rowp, payl, features, (float*)d_out);
}

// Round 6
// 610.672 us; speedup vs baseline: 1.3027x; 1.0301x over previous
//
#include <hip/hip_runtime.h>

#define NN 100000
#define EE 1600000
#define DD 128
#define TD 640
#define EPSV 1e-5f
#define NBLK_SCAN 391   // ceil(NN/256)
#define SB 1024         // stats partial blocks
#define NRANGE 8        // XCD count; node range slice = NN/8
#define RSZ 12500       // NN / NRANGE
#define NCHUNK 256      // edge chunks
#define CSZ 6250        // EE / NCHUNK

typedef __attribute__((ext_vector_type(8))) short bf16x8;
typedef __attribute__((ext_vector_type(4))) float f32x4;

__device__ inline unsigned short f2b(float f) {
  union { float f; unsigned u; } x; x.f = f;
  unsigned r = x.u + 0x7fff + ((x.u >> 16) & 1);
  return (unsigned short)(r >> 16);
}
__device__ inline float b2f(unsigned short u) {
  union { unsigned u; float f; } x; x.u = ((unsigned)u) << 16;
  return x.f;
}

// ---------- BN stats, stage 1 (fp32 input)
__global__ __launch_bounds__(256) void k_stats_partial(const float* __restrict__ x,
    float* __restrict__ ps, float* __restrict__ pq) {
  float s0=0.f,s1=0.f,s2=0.f,s3=0.f,q0=0.f,q1=0.f,q2=0.f,q3=0.f;
  const float4* x4 = reinterpret_cast<const float4*>(x);
  const int total = NN * DD / 4;
  for (int i = blockIdx.x * 256 + threadIdx.x; i < total; i += SB * 256) {
    float4 v = x4[i];
    s0 += v.x; s1 += v.y; s2 += v.z; s3 += v.w;
    q0 += v.x*v.x; q1 += v.y*v.y; q2 += v.z*v.z; q3 += v.w*v.w;
  }
  __shared__ float ls[256], lq[256];
  int t = threadIdx.x;
  float sv[4] = {s0,s1,s2,s3}, qv[4] = {q0,q1,q2,q3};
#pragma unroll
  for (int j = 0; j < 4; ++j) {
    ls[t] = sv[j]; lq[t] = qv[j];
    __syncthreads();
    if (t < 32) {
      float a = 0.f, b = 0.f;
#pragma unroll
      for (int k = 0; k < 8; ++k) { a += ls[t + 32*k]; b += lq[t + 32*k]; }
      ps[blockIdx.x * DD + t*4 + j] = a;
      pq[blockIdx.x * DD + t*4 + j] = b;
    }
    __syncthreads();
  }
}

// ---------- BN stats, stage 1 (bf16 input)
__global__ __launch_bounds__(256) void k_stats_partial_bf(const unsigned short* __restrict__ x,
    float* __restrict__ ps, float* __restrict__ pq) {
  float s0=0.f,s1=0.f,s2=0.f,s3=0.f,q0=0.f,q1=0.f,q2=0.f,q3=0.f;
  const ushort4* x4 = reinterpret_cast<const ushort4*>(x);
  const int total = NN * DD / 4;
  for (int i = blockIdx.x * 256 + threadIdx.x; i < total; i += SB * 256) {
    ushort4 u = x4[i];
    float vx = b2f(u.x), vy = b2f(u.y), vz = b2f(u.z), vw = b2f(u.w);
    s0 += vx; s1 += vy; s2 += vz; s3 += vw;
    q0 += vx*vx; q1 += vy*vy; q2 += vz*vz; q3 += vw*vw;
  }
  __shared__ float ls[256], lq[256];
  int t = threadIdx.x;
  float sv[4] = {s0,s1,s2,s3}, qv[4] = {q0,q1,q2,q3};
#pragma unroll
  for (int j = 0; j < 4; ++j) {
    ls[t] = sv[j]; lq[t] = qv[j];
    __syncthreads();
    if (t < 32) {
      float a = 0.f, b = 0.f;
#pragma unroll
      for (int k = 0; k < 8; ++k) { a += ls[t + 32*k]; b += lq[t + 32*k]; }
      ps[blockIdx.x * DD + t*4 + j] = a;
      pq[blockIdx.x * DD + t*4 + j] = b;
    }
    __syncthreads();
  }
}

// ---------- BN stats, stage 2
__global__ __launch_bounds__(1024) void k_stats_final(const float* __restrict__ ps,
    const float* __restrict__ pq, const float* __restrict__ g,
    const float* __restrict__ be, float* __restrict__ ssb) {
  __shared__ float ls[1024], lq[1024];
  int t = threadIdx.x;
  int col = t & 127, seg = t >> 7;
  float s = 0.f, q = 0.f;
  for (int b = seg; b < SB; b += 8) { s += ps[b * DD + col]; q += pq[b * DD + col]; }
  ls[t] = s; lq[t] = q;
  __syncthreads();
  if (t < 128) {
#pragma unroll
    for (int k = 1; k < 8; ++k) { s += ls[t + 128*k]; q += lq[t + 128*k]; }
    float mean = s * (1.0f / NN);
    float var  = q * (1.0f / NN) - mean * mean;
    float sc = g[t] * rsqrtf(var + EPSV);
    ssb[t] = sc;
    ssb[DD + t] = be[t] - mean * sc;
  }
}

// ---------- fused BN+ReLU+bf16 cast (fp32 input)
__global__ __launch_bounds__(256) void k_act(const float* __restrict__ x,
    const float* __restrict__ ss, unsigned short* __restrict__ A) {
  int i = blockIdx.x * 256 + threadIdx.x;  // [0, NN*DD/4) exactly
  float4 v = reinterpret_cast<const float4*>(x)[i];
  int c4 = (i & 31) * 4;
  float s0 = ss[c4+0], s1 = ss[c4+1], s2 = ss[c4+2], s3 = ss[c4+3];
  float h0 = ss[DD+c4+0], h1 = ss[DD+c4+1], h2 = ss[DD+c4+2], h3 = ss[DD+c4+3];
  ushort4 o;
  o.x = f2b(fmaxf(0.f, v.x * s0 + h0));
  o.y = f2b(fmaxf(0.f, v.y * s1 + h1));
  o.z = f2b(fmaxf(0.f, v.z * s2 + h2));
  o.w = f2b(fmaxf(0.f, v.w * s3 + h3));
  reinterpret_cast<ushort4*>(A)[i] = o;
}

// ---------- fused BN+ReLU+bf16 cast (bf16 input)
__global__ __launch_bounds__(256) void k_act_bf(const unsigned short* __restrict__ x,
    const float* __restrict__ ss, unsigned short* __restrict__ A) {
  int i = blockIdx.x * 256 + threadIdx.x;
  ushort4 u = reinterpret_cast<const ushort4*>(x)[i];
  int c4 = (i & 31) * 4;
  float s0 = ss[c4+0], s1 = ss[c4+1], s2 = ss[c4+2], s3 = ss[c4+3];
  float h0 = ss[DD+c4+0], h1 = ss[DD+c4+1], h2 = ss[DD+c4+2], h3 = ss[DD+c4+3];
  ushort4 o;
  o.x = f2b(fmaxf(0.f, b2f(u.x) * s0 + h0));
  o.y = f2b(fmaxf(0.f, b2f(u.y) * s1 + h1));
  o.z = f2b(fmaxf(0.f, b2f(u.z) * s2 + h2));
  o.w = f2b(fmaxf(0.f, b2f(u.w) * s3 + h3));
  reinterpret_cast<ushort4*>(A)[i] = o;
}

// ---------- W -> B2 rearrange + bf16: B2[d][t*128+k] = W[(t*128+d)*128+k]
__global__ void k_cvt_b2(const float* __restrict__ w, unsigned short* __restrict__ o) {
  int i = blockIdx.x * 256 + threadIdx.x;  // [0, 20480)
  int tt = i >> 12;
  int rem = i & 4095;
  int d = rem >> 5, j = rem & 31;
  float4 v = reinterpret_cast<const float4*>(w)[i];
  ushort4 u; u.x = f2b(v.x); u.y = f2b(v.y); u.z = f2b(v.z); u.w = f2b(v.w);
  reinterpret_cast<ushort4*>(o)[d * 160 + tt * 32 + j] = u;
}

// ---------- CSR build
__global__ void k_zero(int* p, int n) {
  int i = blockIdx.x * 256 + threadIdx.x;
  if (i < n) p[i] = 0;
}
__global__ __launch_bounds__(256) void k_hist(const int* __restrict__ dst,
    int* __restrict__ cnt) {
  const int range = blockIdx.x & (NRANGE - 1);
  const int chunk = blockIdx.x >> 3;
  const int lo = range * RSZ;
  const int base = chunk * CSZ;
  for (int i = base + threadIdx.x; i < base + CSZ; i += 256) {
    int d = dst[i];
    if ((unsigned)(d - lo) < RSZ) atomicAdd(&cnt[d], 1);
  }
}
__global__ __launch_bounds__(256) void k_scan_blk(const int* __restrict__ cnt, int* __restrict__ bsum) {
  __shared__ int sh[256];
  int idx = blockIdx.x * 256 + threadIdx.x;
  sh[threadIdx.x] = (idx < NN) ? cnt[idx] : 0;
  __syncthreads();
  for (int off = 128; off > 0; off >>= 1) {
    if (threadIdx.x < off) sh[threadIdx.x] += sh[threadIdx.x + off];
    __syncthreads();
  }
  if (threadIdx.x == 0) bsum[blockIdx.x] = sh[0];
}
__global__ __launch_bounds__(512) void k_scan_top(int* __restrict__ bsum) {
  __shared__ int sh[512];
  int t = threadIdx.x;
  int v = (t < NBLK_SCAN) ? bsum[t] : 0;
  sh[t] = v;
  __syncthreads();
  for (int off = 1; off < 512; off <<= 1) {
    int add = (t >= off) ? sh[t - off] : 0;
    __syncthreads();
    sh[t] += add;
    __syncthreads();
  }
  if (t < NBLK_SCAN) bsum[t] = sh[t] - v;  // exclusive
}
__global__ __launch_bounds__(256) void k_scan_fin(const int* __restrict__ cnt,
    const int* __restrict__ bsum, int* __restrict__ row_ptr, int* __restrict__ cursor) {
  __shared__ int sh[256];
  int idx = blockIdx.x * 256 + threadIdx.x;
  int v = (idx < NN) ? cnt[idx] : 0;
  sh[threadIdx.x] = v;
  __syncthreads();
  for (int off = 1; off < 256; off <<= 1) {
    int add = (threadIdx.x >= off) ? sh[threadIdx.x - off] : 0;
    __syncthreads();
    sh[threadIdx.x] += add;
    __syncthreads();
  }
  int excl = bsum[blockIdx.x] + sh[threadIdx.x] - v;
  if (idx < NN) { row_ptr[idx] = excl; cursor[idx] = excl; }
  if (idx == NN - 1) row_ptr[NN] = excl + v;
}
__global__ __launch_bounds__(256) void k_scatter(const int* __restrict__ src,
    const int* __restrict__ dst, const int* __restrict__ et,
    int* __restrict__ cursor, int* __restrict__ payload) {
  const int range = blockIdx.x & (NRANGE - 1);
  const int chunk = blockIdx.x >> 3;
  const int lo = range * RSZ;
  const int base = chunk * CSZ;
  for (int i = base + threadIdx.x; i < base + CSZ; i += 256) {
    int d = dst[i];
    if ((unsigned)(d - lo) < RSZ) {
      int pos = atomicAdd(&cursor[d], 1);
      payload[pos] = (src[i] << 3) | et[i];
    }
  }
}

// ---------- K1: per-dst aggregate of h rows by type.
// G[n, t*128+c] = sum of Ab[src, c] over edges (src->n, type t); cntb[n*8+t] = #edges.
// 1 wave per node (lane owns cols 2l, 2l+1); random reads hit the 25.6 MB
// L2/L3-resident Ab instead of the 128 MB H of the old formulation.
__global__ __launch_bounds__(256) void k_agg(const unsigned short* __restrict__ Ab,
    const int* __restrict__ rp, const int* __restrict__ pl,
    unsigned short* __restrict__ G, int* __restrict__ cntb) {
  const int n = blockIdx.x * 4 + (threadIdx.x >> 6);
  const int l = threadIdx.x & 63;
  const int s = rp[n], e = rp[n + 1];
  float a00=0.f,a01=0.f,a10=0.f,a11=0.f,a20=0.f,a21=0.f,a30=0.f,a31=0.f,a40=0.f,a41=0.f;
  int c0=0,c1=0,c2=0,c3=0,c4=0;
  int j = s;
  for (; j + 1 < e; j += 2) {
    int p0 = pl[j], p1 = pl[j + 1];
    ushort2 u0 = *reinterpret_cast<const ushort2*>(Ab + (p0 >> 3) * DD + 2 * l);
    ushort2 u1 = *reinterpret_cast<const ushort2*>(Ab + (p1 >> 3) * DD + 2 * l);
    float x0 = b2f(u0.x), x1 = b2f(u0.y);
    switch (p0 & 7) {
      case 0: a00 += x0; a01 += x1; c0++; break;
      case 1: a10 += x0; a11 += x1; c1++; break;
      case 2: a20 += x0; a21 += x1; c2++; break;
      case 3: a30 += x0; a31 += x1; c3++; break;
      default: a40 += x0; a41 += x1; c4++; break;
    }
    float z0 = b2f(u1.x), z1 = b2f(u1.y);
    switch (p1 & 7) {
      case 0: a00 += z0; a01 += z1; c0++; break;
      case 1: a10 += z0; a11 += z1; c1++; break;
      case 2: a20 += z0; a21 += z1; c2++; break;
      case 3: a30 += z0; a31 += z1; c3++; break;
      default: a40 += z0; a41 += z1; c4++; break;
    }
  }
  if (j < e) {
    int p0 = pl[j];
    ushort2 u0 = *reinterpret_cast<const ushort2*>(Ab + (p0 >> 3) * DD + 2 * l);
    float x0 = b2f(u0.x), x1 = b2f(u0.y);
    switch (p0 & 7) {
      case 0: a00 += x0; a01 += x1; c0++; break;
      case 1: a10 += x0; a11 += x1; c1++; break;
      case 2: a20 += x0; a21 += x1; c2++; break;
      case 3: a30 += x0; a31 += x1; c3++; break;
      default: a40 += x0; a41 += x1; c4++; break;
    }
  }
  unsigned short* gp = G + n * TD + 2 * l;
  ushort2 o;
  o.x = f2b(a00); o.y = f2b(a01); *reinterpret_cast<ushort2*>(gp + 0 * DD) = o;
  o.x = f2b(a10); o.y = f2b(a11); *reinterpret_cast<ushort2*>(gp + 1 * DD) = o;
  o.x = f2b(a20); o.y = f2b(a21); *reinterpret_cast<ushort2*>(gp + 2 * DD) = o;
  o.x = f2b(a30); o.y = f2b(a31); *reinterpret_cast<ushort2*>(gp + 3 * DD) = o;
  o.x = f2b(a40); o.y = f2b(a41); *reinterpret_cast<ushort2*>(gp + 4 * DD) = o;
  if (l < 5) {
    int c = (l == 0) ? c0 : (l == 1) ? c1 : (l == 2) ? c2 : (l == 3) ? c3 : c4;
    cntb[n * 8 + l] = c;
  }
}

// ---------- K2: y[N,128] = G[N,640] x B2^T-ish + cnt*b (+ base). RND=0: bf16 out,
// no base (y1). RND=1: fp32 out, base=features (d_out). Clone of validated R4
// k_gemm structure: K=640 in 10 LDS-staged slices, XOR swizzle, dbuf.
template<int RND>
__global__ __launch_bounds__(256) void k_gemm2(const unsigned short* __restrict__ G,
    const unsigned short* __restrict__ B2, const float* __restrict__ bias,
    const int* __restrict__ cntb, const float* __restrict__ base,
    void* __restrict__ out) {
  __shared__ unsigned short wlds[2][8192];  // 2 x 16 KB
  const int t = threadIdx.x;
  const int l = t & 63;
  const int w = t >> 6;
  const int lm = l & 15;
  const int hi = l >> 4;
  const int R = blockIdx.x * 64 + w * 16;

  int arow = R + lm; if (arow >= NN) arow = NN - 1;
  const unsigned short* aptr = G + arow * TD + hi * 8;

  // stage slice 0: B2 cols-block [128 rows x 64 K] -> 16 KB
#pragma unroll
  for (int k = 0; k < 4; ++k) {
    int idx = k * 256 + t;
    int c = idx >> 3, sub = idx & 7;
    float4 v = *reinterpret_cast<const float4*>(
        reinterpret_cast<const char*>(B2) + c * 1280 + sub * 16);
    *reinterpret_cast<float4*>(
        reinterpret_cast<char*>(wlds[0]) + c * 128 + ((sub * 16) ^ ((c & 7) << 4))) = v;
  }
  __syncthreads();

  f32x4 acc[8] = {};
#pragma unroll 1
  for (int ks = 0; ks < 10; ++ks) {
    const int buf = ks & 1;
    if (ks < 9) {
#pragma unroll
      for (int k = 0; k < 4; ++k) {
        int idx = k * 256 + t;
        int c = idx >> 3, sub = idx & 7;
        float4 v = *reinterpret_cast<const float4*>(
            reinterpret_cast<const char*>(B2) + c * 1280 + (ks + 1) * 128 + sub * 16);
        *reinterpret_cast<float4*>(
            reinterpret_cast<char*>(wlds[buf ^ 1]) + c * 128 + ((sub * 16) ^ ((c & 7) << 4))) = v;
      }
    }
    bf16x8 af0 = *reinterpret_cast<const bf16x8*>(aptr + ks * 64);
    bf16x8 af1 = *reinterpret_cast<const bf16x8*>(aptr + ks * 64 + 32);
#pragma unroll
    for (int f = 0; f < 8; ++f) {
      int rr = f * 16 + lm;
      bf16x8 b0 = *reinterpret_cast<const bf16x8*>(
          reinterpret_cast<char*>(wlds[buf]) + rr * 128 + ((hi * 16) ^ ((rr & 7) << 4)));
      bf16x8 b1 = *reinterpret_cast<const bf16x8*>(
          reinterpret_cast<char*>(wlds[buf]) + rr * 128 + ((64 + hi * 16) ^ ((rr & 7) << 4)));
      acc[f] = __builtin_amdgcn_mfma_f32_16x16x32_bf16(af0, b0, acc[f], 0, 0, 0);
      acc[f] = __builtin_amdgcn_mfma_f32_16x16x32_bf16(af1, b1, acc[f], 0, 0, 0);
    }
    __syncthreads();
  }

  // epilogue: + sum_t cnt[row][t]*b[t*128+col] (+ base), write
  const int r0 = R + hi * 4;
  float cn[4][5];
#pragma unroll
  for (int r = 0; r < 4; ++r) {
    int row = r0 + r; if (row >= NN) row = NN - 1;
#pragma unroll
    for (int tt = 0; tt < 5; ++tt) cn[r][tt] = (float)cntb[row * 8 + tt];
  }
#pragma unroll
  for (int f = 0; f < 8; ++f) {
    int col = f * 16 + lm;
    float bb0 = bias[col], bb1 = bias[128 + col], bb2 = bias[256 + col],
          bb3 = bias[384 + col], bb4 = bias[512 + col];
#pragma unroll
    for (int r = 0; r < 4; ++r) {
      int row = r0 + r;
      if (row < NN) {
        float v = acc[f][r] + cn[r][0]*bb0 + cn[r][1]*bb1 + cn[r][2]*bb2
                            + cn[r][3]*bb3 + cn[r][4]*bb4;
        if (RND == 1) {
          v += base[row * DD + col];
          reinterpret_cast<float*>(out)[row * DD + col] = v;
        } else {
          reinterpret_cast<unsigned short*>(out)[row * DD + col] = f2b(v);
        }
      }
    }
  }
}

extern "C" void kernel_launch(void* const* d_in, const int* in_sizes, int n_in,
                              void* d_out, int out_size, void* d_ws, size_t ws_size,
                              hipStream_t stream) {
  const float* features = (const float*)d_in[0];
  const int*   src   = (const int*)d_in[1];
  const int*   dst   = (const int*)d_in[2];
  const int*   etype = (const int*)d_in[3];
  const float* w1  = (const float*)d_in[4];
  const float* b1  = (const float*)d_in[5];
  const float* g1  = (const float*)d_in[6];
  const float* be1 = (const float*)d_in[7];
  const float* w2  = (const float*)d_in[8];
  const float* b2  = (const float*)d_in[9];
  const float* g2  = (const float*)d_in[10];
  const float* be2 = (const float*)d_in[11];

  char* ws = (char*)d_ws;
  unsigned short* Ab   = (unsigned short*)(ws + 0);            // 25,600,000 B
  float*          ps   = (float*)(ws + 0);                     // aliases Ab (dead before k_act)
  float*          pq   = (float*)(ws + 524288);
  unsigned short* G    = (unsigned short*)(ws + 25600000);     // 128,000,000 B
  unsigned short* y1   = (unsigned short*)(ws + 153600000);    // 25,600,000 B (bf16)
  unsigned short* b2a  = (unsigned short*)(ws + 179200000);    // 163,840 B
  unsigned short* b2b  = (unsigned short*)(ws + 179363840);    // 163,840 B
  float*          ssb  = (float*)(ws + 179527680);             // 1,024 B
  int*            rowp = (int*)(ws + 179528704);               // 400,016 B
  int*            curs = (int*)(ws + 179928720);               // 400,000 B
  int*            payl = (int*)(ws + 180328720);               // 6,400,000 B
  int*            bsum = (int*)(ws + 186728720);               // 2,048 B
  int*            cntb = (int*)(ws + 186730768);               // 3,200,000 B
  // total: 189,930,768 B  (< previously-passing 212.6 MB footprint)

  // CSR build (shared by both rounds)
  k_zero<<<(NN + 255) / 256, 256, 0, stream>>>(curs, NN);
  k_hist<<<NRANGE * NCHUNK, 256, 0, stream>>>(dst, curs);
  k_scan_blk<<<NBLK_SCAN, 256, 0, stream>>>(curs, bsum);
  k_scan_top<<<1, 512, 0, stream>>>(bsum);
  k_scan_fin<<<NBLK_SCAN, 256, 0, stream>>>(curs, bsum, rowp, curs);
  k_scatter<<<NRANGE * NCHUNK, 256, 0, stream>>>(src, dst, etype, curs, payl);

  // weights -> rearranged bf16 B2
  k_cvt_b2<<<80, 256, 0, stream>>>(w1, b2a);
  k_cvt_b2<<<80, 256, 0, stream>>>(w2, b2b);

  // ---- round 1
  k_stats_partial<<<SB, 256, 0, stream>>>(features, ps, pq);
  k_stats_final<<<1, 1024, 0, stream>>>(ps, pq, g1, be1, ssb);
  k_act<<<12500, 256, 0, stream>>>(features, ssb, Ab);
  k_agg<<<NN / 4, 256, 0, stream>>>(Ab, rowp, payl, G, cntb);
  k_gemm2<0><<<1563, 256, 0, stream>>>(G, b2a, b1, cntb, nullptr, y1);

  // ---- round 2
  k_stats_partial_bf<<<SB, 256, 0, stream>>>(y1, ps, pq);
  k_stats_final<<<1, 1024, 0, stream>>>(ps, pq, g2, be2, ssb);
  k_act_bf<<<12500, 256, 0, stream>>>(y1, ssb, Ab);
  k_agg<<<NN / 4, 256, 0, stream>>>(Ab, rowp, payl, G, cntb);
  k_gemm2<1><<<1563, 256, 0, stream>>>(G, b2b, b2, cntb, features, d_out);
}